// Round 5
// baseline (918.162 us; speedup 1.0000x reference)
//
#include <hip/hip_runtime.h>
#include <cstddef>

#define WIDTH 768
#define NTOK 98      // FD*(L_TOK-1)
#define DH 392       // 4*98
#define KCL 49
#define NGRP 384     // B*AFTER_F

typedef unsigned short ushort_t;
typedef unsigned int uint_t;
typedef __attribute__((ext_vector_type(4))) float f32x4;
typedef __attribute__((ext_vector_type(8))) short bf16x8;

static __device__ __forceinline__ ushort_t f2bf(float f) {
    union { float f; uint_t u; } v; v.f = f;
    uint_t u = v.u;
    uint_t r = (u + 0x7FFFu + ((u >> 16) & 1u)) >> 16;
    return (ushort_t)r;
}
static __device__ __forceinline__ uint_t pack2(float a, float b) {
    return (uint_t)f2bf(a) | ((uint_t)f2bf(b) << 16);
}

// ---------------- Prep: transposed bf16 weights + LN-fold constants ----------------
// w1T[400][128]: w1T[j][t] = w1[t][j] (t<98), b1[j] (t==98), else 0; j>=392 rows zero.
// w2T[112][416]: w2T[o][j] = g1[j]*w2[j][o] (j<392), else 0; o>=98 rows zero.
// w3T[64][128]:  w3T[c][j] = g2[j]*w3[j][c] (j<98), else 0 (incl j==98); c>=49 zero.
// bias2t[o] = sum_j be1[j]*w2[j][o] + b2[o]      (112 padded, zeros past 97)
// rowsum2[o] = sum_j g1[j]*w2[j][o]              (112 padded)
// bias3t[c] = sum_j be2[j]*w3[j][c] + b3[c]      (64 padded)
// rowsum3[c] = sum_j g2[j]*w3[j][c]              (64 padded)
__global__ __launch_bounds__(256) void k_prep(
    const float* __restrict__ w1, const float* __restrict__ b1,
    const float* __restrict__ g1, const float* __restrict__ be1,
    const float* __restrict__ w2, const float* __restrict__ b2,
    const float* __restrict__ g2, const float* __restrict__ be2,
    const float* __restrict__ w3, const float* __restrict__ b3,
    ushort_t* __restrict__ w1T, ushort_t* __restrict__ w2T,
    ushort_t* __restrict__ w3T, float* __restrict__ bias2t,
    float* __restrict__ rowsum2, float* __restrict__ rowsum3,
    float* __restrict__ bias3t)
{
    const int tid = threadIdx.x;
    if (blockIdx.x == 0) {
        if (tid < 112) {
            int o = tid;
            float sb = 0.f, sr = 0.f;
            if (o < NTOK) {
                for (int j = 0; j < DH; j++) {
                    float w = w2[j * NTOK + o];
                    sb += be1[j] * w;
                    sr += g1[j] * w;
                }
                sb += b2[o];
            }
            bias2t[o] = sb;
            rowsum2[o] = sr;
        }
        if (tid >= 128 && tid < 192) {
            int c = tid - 128;
            float sb = 0.f, sr = 0.f;
            if (c < KCL) {
                for (int j = 0; j < NTOK; j++) {
                    float w = w3[j * KCL + c];
                    sb += be2[j] * w;
                    sr += g2[j] * w;
                }
                sb += b3[c];
            }
            bias3t[c] = sb;
            rowsum3[c] = sr;
        }
    }

    for (int i = blockIdx.x * 256 + tid; i < 400 * 128; i += 1024) {
        int j = i >> 7, k = i & 127;
        float v = 0.f;
        if (j < DH) {
            if (k < NTOK) v = w1[k * DH + j];
            else if (k == NTOK) v = b1[j];
        }
        w1T[i] = f2bf(v);
    }
    for (int i = blockIdx.x * 256 + tid; i < 112 * 416; i += 1024) {
        int o = i / 416, k = i - o * 416;
        float v = 0.f;
        if (o < NTOK && k < DH) v = g1[k] * w2[k * NTOK + o];
        w2T[i] = f2bf(v);
    }
    for (int i = blockIdx.x * 256 + tid; i < 64 * 128; i += 1024) {
        int c = i >> 7, k = i & 127;
        float v = 0.f;
        if (c < KCL && k < NTOK) v = g2[k] * w3[k * KCL + c];
        w3T[i] = f2bf(v);
    }
}

// ---------------- Fused 3-layer token-MLP via bf16 MFMA, LN folded into GEMMs ----------------
// grid = 384 n * 12 d-blocks; block = 256 (4 waves); wave owns 16 d-cols.
__global__ __launch_bounds__(256, 3) void k_mlp(
    const float* __restrict__ x,
    const ushort_t* __restrict__ w1T, const ushort_t* __restrict__ w2T,
    const ushort_t* __restrict__ w3T, const float* __restrict__ bias2t,
    const float* __restrict__ rowsum2, const float* __restrict__ rowsum3,
    const float* __restrict__ bias3t,
    const float* __restrict__ g3, const float* __restrict__ be3,
    float* __restrict__ cent)
{
    __shared__ alignas(16) char smem[50176];   // sv [0,16384) overlapped by per-wave H regions

    const int tid = threadIdx.x;
    const int wv = tid >> 6;
    const int l = tid & 63;
    const int g = l >> 4;
    const int c16 = l & 15;

    const int n = blockIdx.x / 12;
    const int d0 = (blockIdx.x % 12) * 64;
    const int a = n >> 6, b = n & 63;
    const int bt0 = b * 12 + a * 2;

    // ---- stage V tile [64 d][13 k-octets] bf16, XOR-swizzled 256B rows ----
    {
        const int m = tid & 63;
        for (int oct = (tid >> 6); oct < 13; oct += 4) {
            ushort_t vals[8];
            #pragma unroll
            for (int e = 0; e < 8; e++) {
                int t = oct * 8 + e;
                float v;
                if (t < NTOK) {
                    int f = (t >= KCL), lt = t - f * KCL;
                    v = x[((size_t)(1 + lt) * WIDTH + bt0 + f) * WIDTH + d0 + m];
                } else v = (t == NTOK) ? 1.0f : 0.0f;
                vals[e] = f2bf(v);
            }
            uint4 u;
            u.x = (uint_t)vals[0] | ((uint_t)vals[1] << 16);
            u.y = (uint_t)vals[2] | ((uint_t)vals[3] << 16);
            u.z = (uint_t)vals[4] | ((uint_t)vals[5] << 16);
            u.w = (uint_t)vals[6] | ((uint_t)vals[7] << 16);
            *(uint4*)(smem + m * 256 + ((oct * 16) ^ ((m & 15) << 4))) = u;
        }
    }
    __syncthreads();

    bf16x8 bv[4];
    {
        const int mrow = wv * 16 + c16;
        #pragma unroll
        for (int ks = 0; ks < 4; ks++) {
            int oct = ks * 4 + g; if (oct > 12) oct = 12;   // k>=99: A cols zero
            bv[ks] = *(const bf16x8*)(smem + mrow * 256 + ((oct * 16) ^ ((mrow & 15) << 4)));
        }
    }
    __syncthreads();   // sv region free; reused as per-wave H storage

    char* hbase = smem + wv * 12544 + c16 * 784;   // H1 raw: 392 bf16 per column
    char* h2row = smem + wv * 12544 + c16 * 256;   // H2 raw: 128 bf16, XOR-swizzled

    // ---- GEMM1 (chunked accumulators) + LN1 stats; store RAW H1 ----
    float S1 = 0.f, Q1 = 0.f;
    #pragma unroll
    for (int tc = 0; tc < 25; tc += 5) {
        f32x4 acc[5];
        #pragma unroll
        for (int u = 0; u < 5; u++) acc[u] = (f32x4){0.f, 0.f, 0.f, 0.f};
        #pragma unroll
        for (int ks = 0; ks < 4; ks++) {
            #pragma unroll
            for (int u = 0; u < 5; u++) {
                const bf16x8 av = *(const bf16x8*)(w1T + ((tc + u) * 16 + c16) * 128 + (ks * 4 + g) * 8);
                acc[u] = __builtin_amdgcn_mfma_f32_16x16x32_bf16(av, bv[ks], acc[u], 0, 0, 0);
            }
        }
        #pragma unroll
        for (int u = 0; u < 5; u++) {
            int T = tc + u;
            f32x4 v = acc[u];
            S1 += v.x + v.y + v.z + v.w;
            Q1 += v.x * v.x + v.y * v.y + v.z * v.z + v.w * v.w;
            if (!(T == 24 && g >= 2)) {      // j>=392 outside per-column region
                uint2 uu;
                uu.x = pack2(v.x, v.y);
                uu.y = pack2(v.z, v.w);
                *(uint2*)(hbase + (T * 16 + g * 4) * 2) = uu;
            }
        }
    }
    S1 += __shfl_xor(S1, 16); Q1 += __shfl_xor(Q1, 16);
    S1 += __shfl_xor(S1, 32); Q1 += __shfl_xor(Q1, 32);
    const float mu1 = S1 * (1.f / DH);
    const float rstd1 = rsqrtf(fmaxf(Q1 * (1.f / DH) - mu1 * mu1, 0.f) + 1e-5f);

    // ---- GEMM2 on raw H1; LN1 fold in epilogue; LN2 stats; store RAW H2 ----
    f32x4 acc2[7];
    #pragma unroll
    for (int T = 0; T < 7; T++) acc2[T] = (f32x4){0.f, 0.f, 0.f, 0.f};
    #pragma unroll
    for (int ks = 0; ks < 13; ks++) {
        int oct = ks * 4 + g; if (oct > 48) oct = 48;   // j>=392: A cols zero
        const bf16x8 bvv = *(const bf16x8*)(hbase + oct * 16);
        #pragma unroll
        for (int T = 0; T < 7; T++) {
            const bf16x8 av = *(const bf16x8*)(w2T + (T * 16 + c16) * 416 + (ks * 4 + g) * 8);
            acc2[T] = __builtin_amdgcn_mfma_f32_16x16x32_bf16(av, bvv, acc2[T], 0, 0, 0);
        }
    }
    float S2 = 0.f, Q2 = 0.f;
    #pragma unroll
    for (int T = 0; T < 7; T++) {
        const int o0 = T * 16 + g * 4;
        const float4 bs = *(const float4*)(bias2t + o0);
        const float4 rs = *(const float4*)(rowsum2 + o0);
        f32x4 v = acc2[T];
        v.x = rstd1 * (v.x - mu1 * rs.x) + bs.x;
        v.y = rstd1 * (v.y - mu1 * rs.y) + bs.y;
        v.z = rstd1 * (v.z - mu1 * rs.z) + bs.z;
        v.w = rstd1 * (v.w - mu1 * rs.w) + bs.w;
        acc2[T] = v;
        S2 += v.x + v.y + v.z + v.w;
        Q2 += v.x * v.x + v.y * v.y + v.z * v.z + v.w * v.w;
    }
    S2 += __shfl_xor(S2, 16); Q2 += __shfl_xor(Q2, 16);
    S2 += __shfl_xor(S2, 32); Q2 += __shfl_xor(Q2, 32);
    const float mu2 = S2 * (1.f / NTOK);
    const float rstd2 = rsqrtf(fmaxf(Q2 * (1.f / NTOK) - mu2 * mu2, 0.f) + 1e-5f);
    {
        const int swz = (c16 & 7) << 4;
        #pragma unroll
        for (int T = 0; T < 7; T++) {
            f32x4 v = acc2[T];
            uint2 uu;
            uu.x = pack2(v.x, v.y);     // o>=98 values are exactly 0 (padded weights)
            uu.y = pack2(v.z, v.w);
            *(uint2*)(h2row + (((T * 16 + g * 4) * 2) ^ swz)) = uu;
        }
        uint2 z; z.x = 0u; z.y = 0u;
        *(uint2*)(h2row + (((112 + g * 4) * 2) ^ swz)) = z;
    }

    // ---- GEMM3 on raw H2; LN2 fold; LN3 in-register; store centroids ----
    f32x4 acc3[4];
    #pragma unroll
    for (int T = 0; T < 4; T++) acc3[T] = (f32x4){0.f, 0.f, 0.f, 0.f};
    {
        const int swz = (c16 & 7) << 4;
        #pragma unroll
        for (int ks = 0; ks < 4; ks++) {
            const int oct = ks * 4 + g;
            const bf16x8 bvv = *(const bf16x8*)(h2row + ((oct * 16) ^ swz));
            #pragma unroll
            for (int T = 0; T < 4; T++) {
                const bf16x8 av = *(const bf16x8*)(w3T + (T * 16 + c16) * 128 + oct * 8);
                acc3[T] = __builtin_amdgcn_mfma_f32_16x16x32_bf16(av, bvv, acc3[T], 0, 0, 0);
            }
        }
    }
    float S3 = 0.f, Q3 = 0.f;
    #pragma unroll
    for (int T = 0; T < 4; T++) {
        const int c0 = T * 16 + g * 4;
        const float4 bs = *(const float4*)(bias3t + c0);
        const float4 rs = *(const float4*)(rowsum3 + c0);
        f32x4 v = acc3[T];
        v.x = rstd2 * (v.x - mu2 * rs.x) + bs.x;
        v.y = rstd2 * (v.y - mu2 * rs.y) + bs.y;
        v.z = rstd2 * (v.z - mu2 * rs.z) + bs.z;
        v.w = rstd2 * (v.w - mu2 * rs.w) + bs.w;
        acc3[T] = v;
        S3 += v.x + v.y + v.z + v.w;
        Q3 += v.x * v.x + v.y * v.y + v.z * v.z + v.w * v.w;
    }
    S3 += __shfl_xor(S3, 16); Q3 += __shfl_xor(Q3, 16);
    S3 += __shfl_xor(S3, 32); Q3 += __shfl_xor(Q3, 32);
    const float mu3 = S3 * (1.f / KCL);
    const float rstd3 = rsqrtf(fmaxf(Q3 * (1.f / KCL) - mu3 * mu3, 0.f) + 1e-5f);
    {
        const size_t cbase = (size_t)n * KCL * WIDTH + d0 + wv * 16 + c16;
        #pragma unroll
        for (int T = 0; T < 4; T++) {
            const int c0 = T * 16 + g * 4;
            #pragma unroll
            for (int r = 0; r < 4; r++) {
                const int c = c0 + r;
                if (c < KCL) {
                    float val = (acc3[T][r] - mu3) * rstd3 * g3[c] + be3[c];
                    cent[cbase + (size_t)c * WIDTH] = val;
                }
            }
        }
    }
}

// ---------------- distances, min/argmin (unchanged fp32) ----------------
__global__ __launch_bounds__(256) void k_dist(
    const float* __restrict__ x, const float* __restrict__ cent,
    float* __restrict__ mind, int* __restrict__ assignp)
{
    int wid = blockIdx.x * 4 + (threadIdx.x >> 6);
    int lane = threadIdx.x & 63;
    int n = wid / 25, g = wid - n * 25;
    int t0 = g * 4;
    int a = n >> 6, b = n & 63;
    int bt0 = b * 12 + a * 2;

    float d[4][12];
    #pragma unroll
    for (int tt = 0; tt < 4; tt++) {
        int t = t0 + tt;
        bool valid = t < NTOK;
        int te = valid ? t : 0;
        int f = te / KCL, l = te - f * KCL;
        const float* src = x + ((size_t)(1 + l) * WIDTH + bt0 + f) * WIDTH + lane;
        #pragma unroll
        for (int i = 0; i < 12; i++) d[tt][i] = valid ? src[i * 64] : 0.f;
    }
    float nd[4];
    #pragma unroll
    for (int tt = 0; tt < 4; tt++) {
        float s = 0.f;
        #pragma unroll
        for (int i = 0; i < 12; i++) s = fmaf(d[tt][i], d[tt][i], s);
        #pragma unroll
        for (int o = 32; o > 0; o >>= 1) s += __shfl_xor(s, o);
        nd[tt] = s;
    }

    float minv[4] = {1e30f, 1e30f, 1e30f, 1e30f};
    int mini[4] = {0, 0, 0, 0};
    for (int k = 0; k < KCL; k++) {
        const float* cr = cent + ((size_t)n * KCL + k) * WIDTH + lane;
        float c[12];
        #pragma unroll
        for (int i = 0; i < 12; i++) c[i] = cr[i * 64];
        float cn = 0.f;
        #pragma unroll
        for (int i = 0; i < 12; i++) cn = fmaf(c[i], c[i], cn);
        float dot[4] = {0.f, 0.f, 0.f, 0.f};
        #pragma unroll
        for (int tt = 0; tt < 4; tt++)
            #pragma unroll
            for (int i = 0; i < 12; i++) dot[tt] = fmaf(d[tt][i], c[i], dot[tt]);
        #pragma unroll
        for (int o = 32; o > 0; o >>= 1) {
            cn += __shfl_xor(cn, o);
            #pragma unroll
            for (int tt = 0; tt < 4; tt++) dot[tt] += __shfl_xor(dot[tt], o);
        }
        #pragma unroll
        for (int tt = 0; tt < 4; tt++) {
            float dist = sqrtf(fmaxf(nd[tt] + cn - 2.f * dot[tt], 0.f));
            if (dist < minv[tt]) { minv[tt] = dist; mini[tt] = k; }
        }
    }
    if (lane == 0) {
        int nt = NTOK - t0; if (nt > 4) nt = 4;
        for (int tt = 0; tt < nt; tt++) {
            mind[n * NTOK + t0 + tt] = minv[tt];
            assignp[n * NTOK + t0 + tt] = mini[tt];
        }
    }
}

// ---------------- medoids, sort, gather, class token ----------------
__global__ __launch_bounds__(256) void k_medoid(
    const float* __restrict__ x, const float* __restrict__ mind,
    const int* __restrict__ assignp, float* __restrict__ out)
{
    __shared__ float smind[NTOK];
    __shared__ int sassign[NTOK];
    __shared__ int med[KCL], sorted[KCL];

    int n = blockIdx.x, tid = threadIdx.x;
    int a = n >> 6, b = n & 63;
    int np = b * 6 + a;
    int bt0 = b * 12 + a * 2;

    if (tid < NTOK) { smind[tid] = mind[n * NTOK + tid]; sassign[tid] = assignp[n * NTOK + tid]; }
    __syncthreads();

    if (tid < KCL) {
        float best = 1e30f; int bi = 0;
        for (int t = 0; t < NTOK; t++)
            if (sassign[t] == tid && smind[t] < best) { best = smind[t]; bi = t; }
        med[tid] = bi;
    }
    __syncthreads();
    if (tid < KCL) {
        int mk = med[tid], rank = 0;
        for (int j = 0; j < KCL; j++) {
            int mj = med[j];
            rank += (mj < mk) || (mj == mk && j < tid);
        }
        sorted[rank] = mk;
    }
    __syncthreads();

    for (int dd = tid; dd < WIDTH; dd += 256)
        out[(size_t)np * WIDTH + dd] =
            0.5f * (x[(size_t)bt0 * WIDTH + dd] + x[(size_t)(bt0 + 1) * WIDTH + dd]);

    for (int k = 0; k < KCL; k++) {
        int m = sorted[k];
        int f = m / KCL, l = m - f * KCL;
        const float* src = x + ((size_t)(1 + l) * WIDTH + bt0 + f) * WIDTH;
        float* dst = out + ((size_t)(1 + k) * NGRP + np) * WIDTH;
        for (int dd = tid; dd < WIDTH; dd += 256) dst[dd] = src[dd];
    }
}

// ---------------- loss reduction ----------------
__global__ __launch_bounds__(256) void k_loss(const float* __restrict__ mind,
                                              float* __restrict__ out_loss)
{
    __shared__ float red[256];
    float s = 0.f;
    for (int i = threadIdx.x; i < NGRP * NTOK; i += 256) s += mind[i];
    red[threadIdx.x] = s;
    __syncthreads();
    for (int o = 128; o > 0; o >>= 1) {
        if (threadIdx.x < o) red[threadIdx.x] += red[threadIdx.x + o];
        __syncthreads();
    }
    if (threadIdx.x == 0) out_loss[0] = red[0] * (1.f / NGRP);
}

extern "C" void kernel_launch(void* const* d_in, const int* in_sizes, int n_in,
                              void* d_out, int out_size, void* d_ws, size_t ws_size,
                              hipStream_t stream)
{
    const float* x   = (const float*)d_in[0];
    const float* w1  = (const float*)d_in[1];
    const float* b1  = (const float*)d_in[2];
    const float* g1  = (const float*)d_in[3];
    const float* be1 = (const float*)d_in[4];
    const float* w2  = (const float*)d_in[5];
    const float* b2  = (const float*)d_in[6];
    const float* g2  = (const float*)d_in[7];
    const float* be2 = (const float*)d_in[8];
    const float* w3  = (const float*)d_in[9];
    const float* b3  = (const float*)d_in[10];
    const float* g3  = (const float*)d_in[11];
    const float* be3 = (const float*)d_in[12];
    float* out = (float*)d_out;

    float* cent = (float*)d_ws;                                  // 384*49*768 f32
    float* mind = cent + (size_t)NGRP * KCL * WIDTH;             // 37632 f32
    int* assignp = (int*)(mind + NGRP * NTOK);                   // 37632 i32
    ushort_t* w1T = (ushort_t*)(assignp + NGRP * NTOK);          // 400*128 bf16
    ushort_t* w2T = w1T + 400 * 128;                             // 112*416 bf16
    ushort_t* w3T = w2T + 112 * 416;                             // 64*128 bf16
    float* bias2t = (float*)(w3T + 64 * 128);                    // 112 f32 (padded)
    float* rowsum2 = bias2t + 112;                               // 112 f32 (padded)
    float* rowsum3 = rowsum2 + 112;                              // 64 f32 (padded)
    float* bias3t = rowsum3 + 64;                                // 64 f32 (padded)

    k_prep<<<4, 256, 0, stream>>>(w1, b1, g1, be1, w2, b2, g2, be2, w3, b3,
                                  w1T, w2T, w3T, bias2t, rowsum2, rowsum3, bias3t);
    k_mlp<<<NGRP * 12, 256, 0, stream>>>(x, w1T, w2T, w3T, bias2t, rowsum2, rowsum3,
                                         bias3t, g3, be3, cent);
    k_dist<<<(NGRP * 25) / 4, 256, 0, stream>>>(x, cent, mind, assignp);
    k_medoid<<<NGRP, 256, 0, stream>>>(x, mind, assignp, out);
    k_loss<<<1, 256, 0, stream>>>(mind, out + (out_size - 1));
}